// Round 3
// baseline (84.822 us; speedup 1.0000x reference)
//
#include <hip/hip_runtime.h>
#include <math.h>

#define B_ 8
#define S_ 2048
#define D_ 128
#define K_ 64
#define SIG_ 0.5f
#define EPS_ 10.0f
#define E_ 2.718281828459045f

#define AL(p) __hip_atomic_load((p), __ATOMIC_RELAXED, __HIP_MEMORY_SCOPE_AGENT)
#define AS(p, v) __hip_atomic_store((p), (v), __ATOMIC_RELAXED, __HIP_MEMORY_SCOPE_AGENT)

// One fused kernel. grid = B*K = 512 blocks x 256 threads.
// Block bx: phase 1 computes class stats for (b=bx>>6, k=bx&63); per-batch
// barrier over the 64 sibling blocks; phase 2 computes the per-anchor loss for
// octets bx*4 .. bx*4+3 (32 anchors), last block reduces the output.
// Co-residency: 512 blocks, <=44KB LDS (3 blk/CU by LDS), 256 thr -> >=2 blk/CU
// guaranteed => the spin barrier cannot deadlock.
__global__ void __launch_bounds__(256) fused_loss(
    const float* __restrict__ F, const float* __restrict__ C,
    const float* __restrict__ phi, const int* __restrict__ L,
    float* __restrict__ fsumK, float* __restrict__ ssumK,
    float* __restrict__ cntK, float* __restrict__ partial,
    int* __restrict__ cnts, float* __restrict__ out) {

    __shared__ float Cs[K_ * 129];   // padded: conflict-free b32 reads
    __shared__ int list[S_];         // 4 segments of 512 (per-wave compaction)
    __shared__ int segc[4];
    __shared__ float red[256];
    __shared__ float red2[256];
    __shared__ float Fa[D_];
    __shared__ float wacc[4];
    __shared__ int isLast;

    int tid = threadIdx.x;
    int bx = blockIdx.x;
    int b = bx >> 6;
    int k = bx & (K_ - 1);
    int lane = tid & 63;
    int wv = tid >> 6;

    // stage centroids (used only after the first __syncthreads)
    for (int i = tid; i < K_ * D_; i += 256)
        Cs[(i >> 7) * 129 + (i & 127)] = C[i];

    // ---- phase 1a: ballot-compacted row list; wave wv scans rounds wv*8..+7
    const int* Lb = L + b * S_;
    unsigned long long lt = (lane == 63) ? 0x7FFFFFFFFFFFFFFFull
                                         : ((1ull << lane) - 1ull);
    int base = 0;
    #pragma unroll
    for (int rr = 0; rr < 8; ++rr) {
        int r = (wv << 3) + rr;
        int lbl = Lb[(r << 6) + lane];
        unsigned long long m = __ballot(lbl == k);
        if (lbl == k) list[(wv << 9) + base + __popcll(m & lt)] = (r << 6) + lane;
        base += __popcll(m);
    }
    if (lane == 0) segc[wv] = base;
    __syncthreads();

    // ---- phase 1b: accumulate class rows; half h covers segments 2h,2h+1
    int h = tid >> 7;
    int d = tid & 127;
    const float* Fb = F + (size_t)b * S_ * D_ + d;
    float fa0 = 0.f, fa1 = 0.f, fq0 = 0.f, fq1 = 0.f;
    #pragma unroll
    for (int sgi = 0; sgi < 2; ++sgi) {
        int seg = h * 2 + sgi;
        int n = segc[seg];
        const int* lp = &list[seg << 9];
        int i = 0;
        for (; i + 2 <= n; i += 2) {
            float v0 = Fb[(size_t)lp[i] * D_];
            float v1 = Fb[(size_t)lp[i + 1] * D_];
            fa0 += v0; fq0 = fmaf(v0, v0, fq0);
            fa1 += v1; fq1 = fmaf(v1, v1, fq1);
        }
        if (i < n) { float v = Fb[(size_t)lp[i] * D_]; fa0 += v; fq0 = fmaf(v, v, fq0); }
    }
    red[tid] = fa0 + fa1;
    red2[tid] = fq0 + fq1;
    __syncthreads();
    int ntot = segc[0] + segc[1] + segc[2] + segc[3];
    if (tid < 128) AS(&fsumK[(size_t)bx * D_ + tid], red[tid] + red[tid + 128]);
    if (tid < 64) {
        float v = red2[tid] + red2[tid + 64] + red2[tid + 128] + red2[tid + 192];
        #pragma unroll
        for (int m = 1; m < 64; m <<= 1) v += __shfl_xor(v, m);
        if (tid == 0) { AS(&ssumK[bx], v); AS(&cntK[bx], (float)ntot); }
    }
    __syncthreads();   // drains all global/atomic writes (vmcnt 0) before publish

    // ---- per-batch barrier over the 64 sibling blocks
    if (tid == 0) {
        __hip_atomic_fetch_add(&cnts[b], 1, __ATOMIC_ACQ_REL, __HIP_MEMORY_SCOPE_AGENT);
        while (__hip_atomic_load(&cnts[b], __ATOMIC_ACQUIRE, __HIP_MEMORY_SCOPE_AGENT) < K_)
            __builtin_amdgcn_s_sleep(2);
    }
    __syncthreads();

    // ---- phase 2 prep: Fa[d] = sum_k fsumK[b,k,d] (split over halves)
    {
        float s = 0.f;
        const float* g = fsumK + (size_t)b * K_ * D_ + (size_t)(h * 32) * D_ + d;
        #pragma unroll 8
        for (int kk = 0; kk < 32; ++kk) s += AL(&g[kk * D_]);
        red[tid] = s;
    }
    __syncthreads();
    if (tid < 128) Fa[tid] = red[tid] + red[tid + 128];
    __syncthreads();

    // per-lane (lane == k) constants
    float c0 = 0.f, c1 = 0.f, c2 = 0.f, c3 = 0.f;
    #pragma unroll
    for (int dd = 0; dd < D_; dd += 4) {
        c0 = fmaf(Cs[lane * 129 + dd + 0], Cs[lane * 129 + dd + 0], c0);
        c1 = fmaf(Cs[lane * 129 + dd + 1], Cs[lane * 129 + dd + 1], c1);
        c2 = fmaf(Cs[lane * 129 + dd + 2], Cs[lane * 129 + dd + 2], c2);
        c3 = fmaf(Cs[lane * 129 + dd + 3], Cs[lane * 129 + dd + 3], c3);
    }
    float csq = (c0 + c1) + (c2 + c3);
    float phv = phi[lane];
    float ssl = AL(&ssumK[b * K_ + lane]);
    float cnl = AL(&cntK[b * K_ + lane]);
    float ssA = ssl;
    #pragma unroll
    for (int m = 1; m < 64; m <<= 1) ssA += __shfl_xor(ssA, m);

    int wid = __builtin_amdgcn_readfirstlane(tid) >> 6;   // SGPR wave id
    int o = bx * 4 + wid;
    int a0 = o * 8;
    const float4* F4 = (const float4*)F;

    // ---- phase A: per-anchor sq / dot(fsumK[lbl]) / dot(Fa); 8 lanes/anchor
    int j_of = lane >> 3, q = lane & 7;
    int a_mine = a0 + j_of;
    int lbl_p = L[a_mine];
    const float4* fr = F4 + (size_t)a_mine * 32;
    const float* fkp = fsumK + (size_t)(b * K_ + lbl_p) * D_;
    const float4* fa4 = (const float4*)Fa;

    float sq_p = 0.f, dk_p = 0.f, da_p = 0.f;
    #pragma unroll
    for (int i = 0; i < 4; ++i) {
        int dq = i * 8 + q;
        float4 fv = fr[dq];
        float4 av = fa4[dq];
        float k0 = AL(&fkp[dq * 4 + 0]);
        float k1v = AL(&fkp[dq * 4 + 1]);
        float k2v = AL(&fkp[dq * 4 + 2]);
        float k3v = AL(&fkp[dq * 4 + 3]);
        sq_p = fmaf(fv.x, fv.x, fmaf(fv.y, fv.y, fmaf(fv.z, fv.z, fmaf(fv.w, fv.w, sq_p))));
        dk_p = fmaf(fv.x, k0, fmaf(fv.y, k1v, fmaf(fv.z, k2v, fmaf(fv.w, k3v, dk_p))));
        da_p = fmaf(fv.x, av.x, fmaf(fv.y, av.y, fmaf(fv.z, av.z, fmaf(fv.w, av.w, da_p))));
    }
    #pragma unroll
    for (int m = 1; m < 8; m <<= 1) {
        sq_p += __shfl_xor(sq_p, m);
        dk_p += __shfl_xor(dk_p, m);
        da_p += __shfl_xor(da_p, m);
    }

    // ---- phase B: centroid dots, lane = k, wave-uniform feature loads
    float facc[8];
    #pragma unroll
    for (int j = 0; j < 8; ++j) facc[j] = 0.f;

    for (int dq = 0; dq < 32; ++dq) {
        float4 fv[8];
        #pragma unroll
        for (int j = 0; j < 8; ++j) fv[j] = F4[(size_t)(a0 + j) * 32 + dq];
        int cbase = lane * 129 + (dq << 2);
        #pragma unroll
        for (int l = 0; l < 4; ++l) {
            float cs = Cs[cbase + l];
            #pragma unroll
            for (int j = 0; j < 8; ++j) {
                float fe = (l == 0) ? fv[j].x : (l == 1) ? fv[j].y : (l == 2) ? fv[j].z : fv[j].w;
                facc[j] = fmaf(fe, cs, facc[j]);
            }
        }
    }

    // ---- phase C: per-anchor scalar epilogue
    float acc = 0.f;
    #pragma unroll
    for (int j = 0; j < 8; ++j) {
        float sq_j = __shfl(sq_p, j * 8);
        float dk_j = __shfl(dk_p, j * 8);
        float da_j = __shfl(da_p, j * 8);
        int lbl_j = __shfl(lbl_p, j * 8);
        float cnt_j = __shfl(cnl, lbl_j);
        float ssm_j = __shfl(ssl, lbl_j);

        float cd2 = (sq_j + csq - 2.f * facc[j]) * (1.f / D_);
        cd2 = fmaxf(cd2, 0.f) / phv;

        float s_cd = cd2;
        #pragma unroll
        for (int m = 1; m < 64; m <<= 1) s_cd += __shfl_xor(s_cd, m);
        float pos_cent = __shfl(cd2, lbl_j);

        float ncx = (s_cd - pos_cent) * (1.f / (K_ - 1));
        float S_same = (cnt_j * sq_j + ssm_j - 2.f * dk_j) * (1.f / D_);
        float S_all = ((float)S_ * sq_j + ssA - 2.f * da_j) * (1.f / D_);
        float pos_x = fmaxf(S_same, 0.f) / fmaxf(cnt_j - 1.f, 1.f);
        float neg_cnt = (float)S_ - cnt_j;
        float neg_x = fmaxf(S_all - S_same, 0.f) / fmaxf(neg_cnt, 1.f);

        float neg_sup = neg_x * logf(neg_x + E_);
        float ncl = ncx * logf(ncx + E_);

        float pa = SIG_ * pos_x + (1.f - SIG_) * pos_cent
                 - (SIG_ * neg_sup + (1.f - SIG_) * ncl) + EPS_;
        if (neg_cnt > 0.5f) acc += pa;
    }

    if (lane == 0) wacc[wid] = acc;
    __syncthreads();

    // ---- last-block final reduce
    if (tid == 0) {
        float blk = wacc[0] + wacc[1] + wacc[2] + wacc[3];
        AS(&partial[bx], blk);
        int old = __hip_atomic_fetch_add(&cnts[8], 1, __ATOMIC_ACQ_REL,
                                         __HIP_MEMORY_SCOPE_AGENT);
        isLast = (old == B_ * K_ - 1) ? 1 : 0;
    }
    __syncthreads();
    if (isLast) {
        float v = 0.f;
        for (int i = tid; i < B_ * K_; i += 256) v += AL(&partial[i]);
        #pragma unroll
        for (int m = 1; m < 64; m <<= 1) v += __shfl_xor(v, m);
        if (lane == 0) wacc[wv] = v;
        __syncthreads();
        if (tid == 0) out[0] = (wacc[0] + wacc[1] + wacc[2] + wacc[3]) * (1.0f / (float)S_);
    }
}

extern "C" void kernel_launch(void* const* d_in, const int* in_sizes, int n_in,
                              void* d_out, int out_size, void* d_ws, size_t ws_size,
                              hipStream_t stream) {
    const float* F = (const float*)d_in[0];    // [B,S,D]
    const float* C = (const float*)d_in[1];    // [K,D]
    const float* phi = (const float*)d_in[2];  // [K]
    const int* L = (const int*)d_in[3];        // [B,S]
    float* out = (float*)d_out;

    float* ws = (float*)d_ws;
    float* fsumK = ws;                                // B*K*D = 65536
    float* ssumK = fsumK + (size_t)B_ * K_ * D_;      // 512
    float* cntK  = ssumK + B_ * K_;                   // 512
    float* partial = cntK + B_ * K_;                  // 512
    int* cnts = (int*)(partial + B_ * K_);            // [0..7]=batch, [8]=fin

    hipMemsetAsync(cnts, 0, 64, stream);
    fused_loss<<<B_ * K_, 256, 0, stream>>>(F, C, phi, L, fsumK, ssumK, cntK,
                                            partial, cnts, out);
}

// Round 4
// 33.681 us; speedup vs baseline: 2.5184x; 2.5184x over previous
//
#include <hip/hip_runtime.h>
#include <math.h>

#define B_ 8
#define S_ 2048
#define D_ 128
#define K_ 64
#define SIG_ 0.5f
#define EPS_ 10.0f
#define E_ 2.718281828459045f

// ---------------- K1: per (b,k) class stats, 4-wave ballot + immediate gather
// grid = B*K blocks (bx = b*K + k), 256 threads (4 waves; wave wv scans rows
// wv*512 .. wv*512+511). Rows matching class k are extracted from the ballot
// mask with uniform bit-scan and gathered immediately (2x 256B coalesced loads).
__global__ void __launch_bounds__(256) k1_stats(
    const float* __restrict__ F, const int* __restrict__ L,
    float* __restrict__ fsumK, float* __restrict__ ssumK, float* __restrict__ cntK,
    int* __restrict__ counter) {
    int bx = blockIdx.x;
    int k = bx & (K_ - 1);
    int b = bx >> 6;
    int tid = threadIdx.x;
    int lane = tid & 63;
    int wv = tid >> 6;

    __shared__ float redF[4][128];
    __shared__ float redS[4];
    __shared__ int   redC[4];

    const int* Lb = L + b * S_;
    const float* Fb = F + (size_t)b * S_ * D_;

    float a0 = 0.f, a1 = 0.f, q0 = 0.f, q1 = 0.f;
    int cnt = 0;
    #pragma unroll
    for (int rr = 0; rr < 8; ++rr) {
        int r = (wv << 3) + rr;
        int lbl = Lb[(r << 6) + lane];
        unsigned long long m = __ballot(lbl == k);
        cnt += (int)__popcll(m);
        while (m) {               // wave-uniform trip count (~1 per round)
            int i = __ffsll((long long)m) - 1;
            m &= m - 1;
            const float* row = Fb + (size_t)((r << 6) + i) * D_;
            float v0 = row[lane];
            float v1 = row[64 + lane];
            a0 += v0; q0 = fmaf(v0, v0, q0);
            a1 += v1; q1 = fmaf(v1, v1, q1);
        }
    }
    float qq = q0 + q1;
    #pragma unroll
    for (int m = 1; m < 64; m <<= 1) qq += __shfl_xor(qq, m);
    redF[wv][lane] = a0;
    redF[wv][64 + lane] = a1;
    if (lane == 0) { redS[wv] = qq; redC[wv] = cnt; }
    __syncthreads();

    if (tid < 128) {
        float s = (redF[0][tid] + redF[1][tid]) + (redF[2][tid] + redF[3][tid]);
        fsumK[(size_t)bx * D_ + tid] = s;
    }
    if (tid == 0) {
        ssumK[bx] = (redS[0] + redS[1]) + (redS[2] + redS[3]);
        cntK[bx] = (float)(redC[0] + redC[1] + redC[2] + redC[3]);
        if (bx == 0) *counter = 0;   // stream-ordered init for k3's last-block reduce
    }
}

// ---------------- K3: main per-anchor kernel + last-block final reduce
// grid = 512 blocks x 256 threads; each wave handles one octet (8 anchors)
__global__ void __launch_bounds__(256) k3_main(
    const float* __restrict__ F, const float* __restrict__ C,
    const float* __restrict__ phi, const int* __restrict__ L,
    const float* __restrict__ fsumK, const float* __restrict__ ssumK,
    const float* __restrict__ cntK, float* __restrict__ partial,
    int* __restrict__ counter, float* __restrict__ out) {

    __shared__ float Cs[K_ * 129];   // bank = (k+d)%32 for b32 reads: conflict-free
    __shared__ float4 redA[256];
    __shared__ float Fa[D_];         // per-batch feature sum
    __shared__ float wacc[4];
    __shared__ int isLast;
    int tid = threadIdx.x;
    int b = blockIdx.x >> 6;         // 64 blocks per batch

    // stage centroids: float4 global loads, scalar LDS stores into padded rows
    {
        const float4* C4 = (const float4*)C;
        #pragma unroll
        for (int it = 0; it < 8; ++it) {
            int i = it * 256 + tid;          // i in [0, 2048)
            float4 v = C4[i];
            float* p = &Cs[(i >> 5) * 129 + ((i & 31) << 2)];
            p[0] = v.x; p[1] = v.y; p[2] = v.z; p[3] = v.w;
        }
    }
    // Fa[d] = sum_k fsumK[b,k,d]: thread t sums 8 k's of one float4 column
    {
        int d4 = tid & 31, kg = tid >> 5;    // 8 k-groups of 8
        const float4* g4 = (const float4*)(fsumK + (size_t)b * K_ * D_) + (size_t)kg * 8 * 32 + d4;
        float4 s; s.x = s.y = s.z = s.w = 0.f;
        #pragma unroll
        for (int kk = 0; kk < 8; ++kk) {
            float4 v = g4[(size_t)kk * 32];
            s.x += v.x; s.y += v.y; s.z += v.z; s.w += v.w;
        }
        redA[tid] = s;
    }
    __syncthreads();
    if (tid < 32) {
        float4 a; a.x = a.y = a.z = a.w = 0.f;
        #pragma unroll
        for (int g = 0; g < 8; ++g) {
            float4 v = redA[g * 32 + tid];
            a.x += v.x; a.y += v.y; a.z += v.z; a.w += v.w;
        }
        ((float4*)Fa)[tid] = a;
    }
    __syncthreads();

    int lane = tid & 63;
    int wv = tid >> 6;

    // per-lane (lane == k) constants
    float c0 = 0.f, c1 = 0.f, c2 = 0.f, c3 = 0.f;
    #pragma unroll
    for (int dd = 0; dd < D_; dd += 4) {
        c0 = fmaf(Cs[lane * 129 + dd + 0], Cs[lane * 129 + dd + 0], c0);
        c1 = fmaf(Cs[lane * 129 + dd + 1], Cs[lane * 129 + dd + 1], c1);
        c2 = fmaf(Cs[lane * 129 + dd + 2], Cs[lane * 129 + dd + 2], c2);
        c3 = fmaf(Cs[lane * 129 + dd + 3], Cs[lane * 129 + dd + 3], c3);
    }
    float csq = (c0 + c1) + (c2 + c3);
    float phv = phi[lane];
    float ssl = ssumK[b * K_ + lane];
    float cnl = cntK[b * K_ + lane];
    float ssA = ssl;
    #pragma unroll
    for (int m = 1; m < 64; m <<= 1) ssA += __shfl_xor(ssA, m);

    int wid = __builtin_amdgcn_readfirstlane(tid) >> 6;   // SGPR wave id
    int o = blockIdx.x * 4 + wid;
    int a0 = o * 8;
    const float4* F4 = (const float4*)F;

    // ---- phase A: per-anchor sq / dot(fsumK[lbl]) / dot(Fa); 8 lanes/anchor
    int j_of = lane >> 3, q = lane & 7;
    int a_mine = a0 + j_of;
    int lbl_p = L[a_mine];
    const float4* fr = F4 + (size_t)a_mine * 32;
    const float4* fk = (const float4*)(fsumK + (size_t)(b * K_ + lbl_p) * D_);
    const float4* fa4 = (const float4*)Fa;

    float sq_p = 0.f, dk_p = 0.f, da_p = 0.f;
    #pragma unroll
    for (int i = 0; i < 4; ++i) {
        int dq = i * 8 + q;
        float4 fv = fr[dq];
        float4 kv = fk[dq];
        float4 av = fa4[dq];
        sq_p = fmaf(fv.x, fv.x, fmaf(fv.y, fv.y, fmaf(fv.z, fv.z, fmaf(fv.w, fv.w, sq_p))));
        dk_p = fmaf(fv.x, kv.x, fmaf(fv.y, kv.y, fmaf(fv.z, kv.z, fmaf(fv.w, kv.w, dk_p))));
        da_p = fmaf(fv.x, av.x, fmaf(fv.y, av.y, fmaf(fv.z, av.z, fmaf(fv.w, av.w, da_p))));
    }
    #pragma unroll
    for (int m = 1; m < 8; m <<= 1) {
        sq_p += __shfl_xor(sq_p, m);
        dk_p += __shfl_xor(dk_p, m);
        da_p += __shfl_xor(da_p, m);
    }

    // ---- phase B: centroid dots, lane = k, wave-uniform feature loads
    float facc[8];
    #pragma unroll
    for (int j = 0; j < 8; ++j) facc[j] = 0.f;

    for (int dq = 0; dq < 32; ++dq) {
        float4 fv[8];
        #pragma unroll
        for (int j = 0; j < 8; ++j) fv[j] = F4[(size_t)(a0 + j) * 32 + dq];
        int cbase = lane * 129 + (dq << 2);
        #pragma unroll
        for (int l = 0; l < 4; ++l) {
            float cs = Cs[cbase + l];
            #pragma unroll
            for (int j = 0; j < 8; ++j) {
                float fe = (l == 0) ? fv[j].x : (l == 1) ? fv[j].y : (l == 2) ? fv[j].z : fv[j].w;
                facc[j] = fmaf(fe, cs, facc[j]);
            }
        }
    }

    // ---- phase C: per-anchor scalar epilogue
    float acc = 0.f;
    #pragma unroll
    for (int j = 0; j < 8; ++j) {
        float sq_j = __shfl(sq_p, j * 8);
        float dk_j = __shfl(dk_p, j * 8);
        float da_j = __shfl(da_p, j * 8);
        int lbl_j = __shfl(lbl_p, j * 8);
        float cnt_j = __shfl(cnl, lbl_j);
        float ssm_j = __shfl(ssl, lbl_j);

        float cd2 = (sq_j + csq - 2.f * facc[j]) * (1.f / D_);
        cd2 = fmaxf(cd2, 0.f) / phv;

        float s_cd = cd2;
        #pragma unroll
        for (int m = 1; m < 64; m <<= 1) s_cd += __shfl_xor(s_cd, m);
        float pos_cent = __shfl(cd2, lbl_j);

        float ncx = (s_cd - pos_cent) * (1.f / (K_ - 1));
        float S_same = (cnt_j * sq_j + ssm_j - 2.f * dk_j) * (1.f / D_);
        float S_all = ((float)S_ * sq_j + ssA - 2.f * da_j) * (1.f / D_);
        float pos_x = fmaxf(S_same, 0.f) / fmaxf(cnt_j - 1.f, 1.f);
        float neg_cnt = (float)S_ - cnt_j;
        float neg_x = fmaxf(S_all - S_same, 0.f) / fmaxf(neg_cnt, 1.f);

        float neg_sup = neg_x * logf(neg_x + E_);
        float ncl = ncx * logf(ncx + E_);

        float pa = SIG_ * pos_x + (1.f - SIG_) * pos_cent
                 - (SIG_ * neg_sup + (1.f - SIG_) * ncl) + EPS_;
        if (neg_cnt > 0.5f) acc += pa;
    }

    if (lane == 0) wacc[wid] = acc;
    __syncthreads();

    // ---- last-block final reduce (agent-scope atomics; proven in round 2)
    if (tid == 0) {
        float blk = wacc[0] + wacc[1] + wacc[2] + wacc[3];
        __hip_atomic_store(&partial[blockIdx.x], blk, __ATOMIC_RELAXED,
                           __HIP_MEMORY_SCOPE_AGENT);
        int old = __hip_atomic_fetch_add(counter, 1, __ATOMIC_ACQ_REL,
                                         __HIP_MEMORY_SCOPE_AGENT);
        isLast = (old == (int)gridDim.x - 1) ? 1 : 0;
    }
    __syncthreads();
    if (isLast) {
        float v = 0.f;
        for (int i = tid; i < 512; i += 256) {
            v += __hip_atomic_load(&partial[i], __ATOMIC_RELAXED,
                                   __HIP_MEMORY_SCOPE_AGENT);
        }
        #pragma unroll
        for (int m = 1; m < 64; m <<= 1) v += __shfl_xor(v, m);
        if (lane == 0) wacc[wv] = v;
        __syncthreads();
        if (tid == 0) out[0] = (wacc[0] + wacc[1] + wacc[2] + wacc[3]) * (1.0f / (float)S_);
    }
}

extern "C" void kernel_launch(void* const* d_in, const int* in_sizes, int n_in,
                              void* d_out, int out_size, void* d_ws, size_t ws_size,
                              hipStream_t stream) {
    const float* F = (const float*)d_in[0];    // [B,S,D]
    const float* C = (const float*)d_in[1];    // [K,D]
    const float* phi = (const float*)d_in[2];  // [K]
    const int* L = (const int*)d_in[3];        // [B,S]
    float* out = (float*)d_out;

    float* ws = (float*)d_ws;
    float* fsumK = ws;                                // B*K*D = 65536
    float* ssumK = fsumK + (size_t)B_ * K_ * D_;      // 512
    float* cntK  = ssumK + B_ * K_;                   // 512
    float* partial = cntK + B_ * K_;                  // 512
    int* counter = (int*)(partial + 512);             // 1

    k1_stats<<<B_ * K_, 256, 0, stream>>>(F, L, fsumK, ssumK, cntK, counter);
    k3_main<<<512, 256, 0, stream>>>(F, C, phi, L, fsumK, ssumK, cntK, partial, counter, out);
}